// Round 1
// baseline (246.853 us; speedup 1.0000x reference)
//
#include <hip/hip_runtime.h>

#define B_ 4
#define T_ 32
#define NF 256
#define D_ 512
#define H_ 8
#define DK 64
#define M_ (B_*T_*NF)   // 32768
#define BT (B_*T_)      // 128

typedef _Float16 f16;
typedef _Float16 f16x8 __attribute__((ext_vector_type(8)));
typedef float f32x4 __attribute__((ext_vector_type(4)));

// ---------------- conversion kernels ----------------

__global__ void cvt_f32_to_f16(const float* __restrict__ src, f16* __restrict__ dst,
                               int n8, float scale) {
    int idx = blockIdx.x * blockDim.x + threadIdx.x;
    int stride = gridDim.x * blockDim.x;
    for (; idx < n8; idx += stride) {
        const float4* s = reinterpret_cast<const float4*>(src + (size_t)idx * 8);
        float4 v0 = s[0], v1 = s[1];
        f16x8 o;
        o[0] = (f16)(v0.x * scale); o[1] = (f16)(v0.y * scale);
        o[2] = (f16)(v0.z * scale); o[3] = (f16)(v0.w * scale);
        o[4] = (f16)(v1.x * scale); o[5] = (f16)(v1.y * scale);
        o[6] = (f16)(v1.z * scale); o[7] = (f16)(v1.w * scale);
        *reinterpret_cast<f16x8*>(dst + (size_t)idx * 8) = o;
    }
}

__global__ void make_mask(const int* __restrict__ adj, float* __restrict__ maskb, int n) {
    int i = blockIdx.x * blockDim.x + threadIdx.x;
    if (i < n) maskb[i] = (adj[i] > 0) ? 0.0f : -1e30f;
}

// ---------------- QKV GEMM ----------------
// A = xh [M][512] fp16, Wh = [1536][512] fp16 (Wq*0.125, Wk, Wv rows).
// q,k -> [BT][H][NF][DK]; v -> transposed [BT][H][DK][NF].

__global__ __launch_bounds__(256) void qkv_gemm(
    const f16* __restrict__ A, const f16* __restrict__ Wh,
    const float* __restrict__ bq, const float* __restrict__ bk, const float* __restrict__ bv,
    f16* __restrict__ qo, f16* __restrict__ ko, f16* __restrict__ vTo)
{
    __shared__ f16 As[128][40];
    __shared__ f16 Bs[128][40];
    const int t = threadIdx.x;
    const int wave = t >> 6, lane = t & 63;
    const int l15 = lane & 15, l4 = lane >> 4;
    const int m0 = blockIdx.x * 128;
    const int n0 = blockIdx.y * 128;
    const int wr = wave >> 1, wc = wave & 1;
    const int srow = t >> 2, sslot = t & 3;

    f32x4 acc[4][4] = {};

    for (int k0 = 0; k0 < 512; k0 += 32) {
        __syncthreads();
        #pragma unroll
        for (int i = 0; i < 2; ++i) {
            int r = srow + i * 64;
            *reinterpret_cast<f16x8*>(&As[r][sslot * 8]) =
                *reinterpret_cast<const f16x8*>(&A[(size_t)(m0 + r) * 512 + k0 + sslot * 8]);
            *reinterpret_cast<f16x8*>(&Bs[r][sslot * 8]) =
                *reinterpret_cast<const f16x8*>(&Wh[(size_t)(n0 + r) * 512 + k0 + sslot * 8]);
        }
        __syncthreads();
        f16x8 a[4], b[4];
        #pragma unroll
        for (int i = 0; i < 4; ++i)
            a[i] = *reinterpret_cast<const f16x8*>(&As[wr * 64 + i * 16 + l15][l4 * 8]);
        #pragma unroll
        for (int j = 0; j < 4; ++j)
            b[j] = *reinterpret_cast<const f16x8*>(&Bs[wc * 64 + j * 16 + l15][l4 * 8]);
        #pragma unroll
        for (int i = 0; i < 4; ++i)
            #pragma unroll
            for (int j = 0; j < 4; ++j)
                acc[i][j] = __builtin_amdgcn_mfma_f32_16x16x32_f16(a[i], b[j], acc[i][j], 0, 0, 0);
    }

    const int which = n0 >> 9;              // 0:q 1:k 2:v
    const float* bias = (which == 0) ? bq : (which == 1) ? bk : bv;
    const float bscale = (which == 0) ? 0.125f : 1.0f;

    #pragma unroll
    for (int i = 0; i < 4; ++i) {
        #pragma unroll
        for (int j = 0; j < 4; ++j) {
            #pragma unroll
            for (int r = 0; r < 4; ++r) {
                int mg = m0 + wr * 64 + i * 16 + l4 * 4 + r;
                int ng = n0 + wc * 64 + j * 16 + l15;
                int ncol = ng & 511;
                float v = acc[i][j][r] + bscale * bias[ncol];
                int bt = mg >> 8, nf = mg & 255;
                int h = ncol >> 6, dk = ncol & 63;
                f16 hv = (f16)v;
                if (which == 0)
                    qo[(((size_t)bt * H_ + h) * NF + nf) * DK + dk] = hv;
                else if (which == 1)
                    ko[(((size_t)bt * H_ + h) * NF + nf) * DK + dk] = hv;
                else
                    vTo[(((size_t)bt * H_ + h) * DK + dk) * NF + nf] = hv;
            }
        }
    }
}

// ---------------- attention ----------------
// One block per (bt, h). q pre-scaled by 1/8. Writes attn_out fp16 [BT][NF][512] at col h*64.

__global__ __launch_bounds__(256) void attn_kernel(
    const f16* __restrict__ qh, const f16* __restrict__ kh, const f16* __restrict__ vT,
    const float* __restrict__ maskb, f16* __restrict__ ao)
{
    __shared__ f16 Ks[256][72];
    __shared__ f16 Vs[64][264];
    __shared__ f16 Ps[4][16][264];

    const int t = threadIdx.x, wave = t >> 6, lane = t & 63;
    const int l15 = lane & 15, l4 = lane >> 4;
    const int bh = blockIdx.x;
    const int bt = bh >> 3, h = bh & 7;
    const f16* qbase = qh + (size_t)bh * NF * DK;
    const f16* kbase = kh + (size_t)bh * NF * DK;
    const f16* vbase = vT + (size_t)bh * DK * NF;

    {   // stage K [256][64] and V^T [64][256]
        int slot = t & 7, row0 = t >> 3;
        #pragma unroll
        for (int i = 0; i < 8; ++i) {
            int r = row0 + i * 32;
            *reinterpret_cast<f16x8*>(&Ks[r][slot * 8]) =
                *reinterpret_cast<const f16x8*>(&kbase[(size_t)r * 64 + slot * 8]);
        }
        int slot2 = t & 31, row2 = t >> 5;
        #pragma unroll
        for (int i = 0; i < 8; ++i) {
            int r = row2 + i * 8;
            *reinterpret_cast<f16x8*>(&Vs[r][slot2 * 8]) =
                *reinterpret_cast<const f16x8*>(&vbase[(size_t)r * 256 + slot2 * 8]);
        }
    }
    __syncthreads();

    for (int s = 0; s < 4; ++s) {
        const int qrow_base = wave * 64 + s * 16;

        f16x8 aq[2];
        #pragma unroll
        for (int kk = 0; kk < 2; ++kk)
            aq[kk] = *reinterpret_cast<const f16x8*>(
                &qbase[(size_t)(qrow_base + l15) * 64 + kk * 32 + l4 * 8]);

        f32x4 sacc[16];
        #pragma unroll
        for (int ct = 0; ct < 16; ++ct) sacc[ct] = (f32x4){0.f, 0.f, 0.f, 0.f};
        #pragma unroll
        for (int ct = 0; ct < 16; ++ct) {
            #pragma unroll
            for (int kk = 0; kk < 2; ++kk) {
                f16x8 bk_ = *reinterpret_cast<const f16x8*>(&Ks[ct * 16 + l15][kk * 32 + l4 * 8]);
                sacc[ct] = __builtin_amdgcn_mfma_f32_16x16x32_f16(aq[kk], bk_, sacc[ct], 0, 0, 0);
            }
        }

        // mask + softmax: lane owns rows l4*4+r, col l15 of each 16-wide tile
        #pragma unroll
        for (int r = 0; r < 4; ++r) {
            int ig = qrow_base + l4 * 4 + r;
            float mx = -1e38f;
            #pragma unroll
            for (int ct = 0; ct < 16; ++ct) {
                float v = sacc[ct][r] + maskb[(size_t)ig * 256 + ct * 16 + l15];
                sacc[ct][r] = v;
                mx = fmaxf(mx, v);
            }
            #pragma unroll
            for (int m = 1; m < 16; m <<= 1) mx = fmaxf(mx, __shfl_xor(mx, m, 64));
            float sum = 0.f;
            #pragma unroll
            for (int ct = 0; ct < 16; ++ct) {
                float p = __expf(sacc[ct][r] - mx);
                sacc[ct][r] = p;
                sum += p;
            }
            #pragma unroll
            for (int m = 1; m < 16; m <<= 1) sum += __shfl_xor(sum, m, 64);
            float rinv = 1.0f / sum;
            #pragma unroll
            for (int ct = 0; ct < 16; ++ct)
                Ps[wave][l4 * 4 + r][ct * 16 + l15] = (f16)(sacc[ct][r] * rinv);
        }
        __syncthreads();   // P visible (and Vs/Ks stable)

        // PV: out [16 rows][64 cols]
        f32x4 oacc[4] = {};
        #pragma unroll
        for (int kk = 0; kk < 8; ++kk) {
            f16x8 ap = *reinterpret_cast<const f16x8*>(&Ps[wave][l15][kk * 32 + l4 * 8]);
            #pragma unroll
            for (int c2 = 0; c2 < 4; ++c2) {
                f16x8 bv_ = *reinterpret_cast<const f16x8*>(&Vs[c2 * 16 + l15][kk * 32 + l4 * 8]);
                oacc[c2] = __builtin_amdgcn_mfma_f32_16x16x32_f16(ap, bv_, oacc[c2], 0, 0, 0);
            }
        }
        #pragma unroll
        for (int c2 = 0; c2 < 4; ++c2)
            #pragma unroll
            for (int r = 0; r < 4; ++r) {
                int nf = qrow_base + l4 * 4 + r;
                int dcol = h * 64 + c2 * 16 + l15;
                ao[((size_t)bt * NF + nf) * 512 + dcol] = (f16)oacc[c2][r];
            }
        __syncthreads();   // before next strip overwrites Ps
    }
}

// ---------------- output projection ----------------

__global__ __launch_bounds__(256) void o_gemm(
    const f16* __restrict__ A, const f16* __restrict__ Wh,
    const float* __restrict__ bo, float* __restrict__ out)
{
    __shared__ f16 As[128][40];
    __shared__ f16 Bs[128][40];
    const int t = threadIdx.x;
    const int wave = t >> 6, lane = t & 63;
    const int l15 = lane & 15, l4 = lane >> 4;
    const int m0 = blockIdx.x * 128;
    const int n0 = blockIdx.y * 128;
    const int wr = wave >> 1, wc = wave & 1;
    const int srow = t >> 2, sslot = t & 3;

    f32x4 acc[4][4] = {};

    for (int k0 = 0; k0 < 512; k0 += 32) {
        __syncthreads();
        #pragma unroll
        for (int i = 0; i < 2; ++i) {
            int r = srow + i * 64;
            *reinterpret_cast<f16x8*>(&As[r][sslot * 8]) =
                *reinterpret_cast<const f16x8*>(&A[(size_t)(m0 + r) * 512 + k0 + sslot * 8]);
            *reinterpret_cast<f16x8*>(&Bs[r][sslot * 8]) =
                *reinterpret_cast<const f16x8*>(&Wh[(size_t)(n0 + r) * 512 + k0 + sslot * 8]);
        }
        __syncthreads();
        f16x8 a[4], b[4];
        #pragma unroll
        for (int i = 0; i < 4; ++i)
            a[i] = *reinterpret_cast<const f16x8*>(&As[wr * 64 + i * 16 + l15][l4 * 8]);
        #pragma unroll
        for (int j = 0; j < 4; ++j)
            b[j] = *reinterpret_cast<const f16x8*>(&Bs[wc * 64 + j * 16 + l15][l4 * 8]);
        #pragma unroll
        for (int i = 0; i < 4; ++i)
            #pragma unroll
            for (int j = 0; j < 4; ++j)
                acc[i][j] = __builtin_amdgcn_mfma_f32_16x16x32_f16(a[i], b[j], acc[i][j], 0, 0, 0);
    }

    #pragma unroll
    for (int i = 0; i < 4; ++i)
        #pragma unroll
        for (int j = 0; j < 4; ++j)
            #pragma unroll
            for (int r = 0; r < 4; ++r) {
                int mg = m0 + wr * 64 + i * 16 + l4 * 4 + r;
                int ng = n0 + wc * 64 + j * 16 + l15;
                out[(size_t)mg * 512 + ng] = acc[i][j][r] + bo[ng];
            }
}

// ---------------- launch ----------------

extern "C" void kernel_launch(void* const* d_in, const int* in_sizes, int n_in,
                              void* d_out, int out_size, void* d_ws, size_t ws_size,
                              hipStream_t stream) {
    const float* x  = (const float*)d_in[0];
    const int*   adj = (const int*)d_in[1];
    const float* Wq = (const float*)d_in[2];
    const float* bq = (const float*)d_in[3];
    const float* Wk = (const float*)d_in[4];
    const float* bk = (const float*)d_in[5];
    const float* Wv = (const float*)d_in[6];
    const float* bv = (const float*)d_in[7];
    const float* Wo = (const float*)d_in[8];
    const float* bo = (const float*)d_in[9];
    float* out = (float*)d_out;

    char* ws = (char*)d_ws;
    f16*   Wh    = (f16*)ws;                                   // [1536][512]
    f16*   Woh   = (f16*)(ws + (size_t)1536 * 512 * 2);        // [512][512]
    float* maskb = (float*)(ws + (size_t)2048 * 512 * 2);      // [256][256]
    f16*   xh    = (f16*)(ws + (size_t)2048 * 512 * 2 + 256 * 256 * 4); // [M][512], reused as attn_out
    f16*   qb    = xh + (size_t)M_ * 512;
    f16*   kb    = qb + (size_t)M_ * 512;
    f16*   vTb   = kb + (size_t)M_ * 512;

    cvt_f32_to_f16<<<2048, 256, 0, stream>>>(x,  xh,  M_ * 512 / 8, 1.0f);
    cvt_f32_to_f16<<<128,  256, 0, stream>>>(Wq, Wh,                512 * 512 / 8, 0.125f);
    cvt_f32_to_f16<<<128,  256, 0, stream>>>(Wk, Wh +  (size_t)512 * 512, 512 * 512 / 8, 1.0f);
    cvt_f32_to_f16<<<128,  256, 0, stream>>>(Wv, Wh + (size_t)1024 * 512, 512 * 512 / 8, 1.0f);
    cvt_f32_to_f16<<<128,  256, 0, stream>>>(Wo, Woh,               512 * 512 / 8, 1.0f);
    make_mask<<<256, 256, 0, stream>>>(adj, maskb, 256 * 256);

    qkv_gemm<<<dim3(M_ / 128, 12), 256, 0, stream>>>(xh, Wh, bq, bk, bv, qb, kb, vTb);
    attn_kernel<<<BT * H_, 256, 0, stream>>>(qb, kb, vTb, maskb, xh);
    o_gemm<<<dim3(M_ / 128, 4), 256, 0, stream>>>(xh, Woh, bo, out);
}

// Round 2
// 223.911 us; speedup vs baseline: 1.1025x; 1.1025x over previous
//
#include <hip/hip_runtime.h>

#define NF 256
#define H_ 8
#define M_ 32768

typedef _Float16 f16;
typedef _Float16 f16x8 __attribute__((ext_vector_type(8)));
typedef float f32x4 __attribute__((ext_vector_type(4)));

#define GLOAD16(src, dst) \
  __builtin_amdgcn_global_load_lds((const __attribute__((address_space(1))) void*)(src), \
                                   (__attribute__((address_space(3))) void*)(dst), 16, 0, 0)

// Stage NR rows x 64 f16 from g[(row0+r)*ld + coff + swz(col)] into linear LDS [NR][64].
// LDS dest is linear (global_load_lds constraint); the XOR swizzle is applied by
// pre-permuting the per-lane GLOBAL source column (rule 21: both-sides-or-neither).
template <int NR>
__device__ __forceinline__ void stage_rows(const f16* __restrict__ g, int ld, int row0, int coff,
                                           f16* ldsb, int wave, int lane) {
    const int rr = wave * 8 + (lane >> 3);
    const int p  = lane & 7;
#pragma unroll
    for (int i = 0; i < NR / 32; ++i) {
        int r = i * 32 + rr;
        int col = ((p ^ (r & 7)) << 3);
        GLOAD16(g + (size_t)(row0 + r) * ld + coff + col, ldsb + (i * 32 + wave * 8) * 64);
    }
}

// ---------------- conversion / prep ----------------

__global__ void cvt_x(const float* __restrict__ src, f16* __restrict__ dst, int n8) {
    int idx = blockIdx.x * blockDim.x + threadIdx.x;
    int stride = gridDim.x * blockDim.x;
    for (; idx < n8; idx += stride) {
        const float4* s = reinterpret_cast<const float4*>(src + (size_t)idx * 8);
        float4 v0 = s[0], v1 = s[1];
        f16x8 o;
        o[0] = (f16)v0.x; o[1] = (f16)v0.y; o[2] = (f16)v0.z; o[3] = (f16)v0.w;
        o[4] = (f16)v1.x; o[5] = (f16)v1.y; o[6] = (f16)v1.z; o[7] = (f16)v1.w;
        *reinterpret_cast<f16x8*>(dst + (size_t)idx * 8) = o;
    }
}

__global__ void prep(const float* __restrict__ Wq, const float* __restrict__ Wk,
                     const float* __restrict__ Wv, const float* __restrict__ Wo,
                     const float* __restrict__ bq, const float* __restrict__ bk,
                     const float* __restrict__ bv, const int* __restrict__ adj,
                     f16* __restrict__ Wh, f16* __restrict__ Woh,
                     float* __restrict__ biasAll, float* __restrict__ maskb) {
    const int tid = blockIdx.x * 256 + threadIdx.x;   // grid = 512 blocks -> 131072 threads
    {
        const float* s; f16* d; float sc = 1.0f;
        int pp = tid >> 15, off = tid & 32767;
        if (pp == 0)      { s = Wq; d = Wh;              sc = 0.125f; }
        else if (pp == 1) { s = Wk; d = Wh + 512 * 512; }
        else if (pp == 2) { s = Wv; d = Wh + 2 * 512 * 512; }
        else              { s = Wo; d = Woh; }
        const float4* sv4 = reinterpret_cast<const float4*>(s + (size_t)off * 8);
        float4 v0 = sv4[0], v1 = sv4[1];
        f16x8 o;
        o[0] = (f16)(v0.x * sc); o[1] = (f16)(v0.y * sc);
        o[2] = (f16)(v0.z * sc); o[3] = (f16)(v0.w * sc);
        o[4] = (f16)(v1.x * sc); o[5] = (f16)(v1.y * sc);
        o[6] = (f16)(v1.z * sc); o[7] = (f16)(v1.w * sc);
        *reinterpret_cast<f16x8*>(d + (size_t)off * 8) = o;
    }
    if (tid < 1536) {
        float v = (tid < 512) ? 0.125f * bq[tid] : (tid < 1024) ? bk[tid - 512] : bv[tid - 1024];
        biasAll[tid] = v;
    }
    if (tid < 65536) maskb[tid] = (adj[tid] > 0) ? 0.0f : -1e30f;
}

// ---------------- fused QKV GEMM ----------------
// A = xh [M][512] f16, W = [1536][512] f16 (0.125*Wq | Wk | Wv rows).
// out = qkv [M][1536] f16 row-major.  128x128 tile, BK=64, 2-phase dbuf gload_lds.

__global__ __launch_bounds__(256) void qkv_gemm(const f16* __restrict__ A, const f16* __restrict__ W,
                                                const float* __restrict__ biasAll,
                                                f16* __restrict__ out) {
    __shared__ f16 lds[32768];           // 2 bufs x (A 8192 + B 8192)
    const int t = threadIdx.x, wave = t >> 6, lane = t & 63;
    const int l15 = lane & 15, l4 = lane >> 4;
    const int m0 = blockIdx.x * 128, n0 = blockIdx.y * 128;
    const int wr = wave >> 1, wc = wave & 1;
    f32x4 acc[4][4] = {};

    stage_rows<128>(A, 512, m0, 0, lds, wave, lane);
    stage_rows<128>(W, 512, n0, 0, lds + 8192, wave, lane);
    __syncthreads();
    int cur = 0;
    for (int kt = 0; kt < 8; ++kt) {
        if (kt < 7) {
            stage_rows<128>(A, 512, m0, (kt + 1) * 64, lds + (cur ^ 1) * 16384, wave, lane);
            stage_rows<128>(W, 512, n0, (kt + 1) * 64, lds + (cur ^ 1) * 16384 + 8192, wave, lane);
        }
        const f16* Ab = lds + cur * 16384;
        const f16* Bb = Ab + 8192;
        f16x8 af[4][2], bf[4][2];
#pragma unroll
        for (int i = 0; i < 4; ++i)
#pragma unroll
            for (int kk = 0; kk < 2; ++kk) {
                int ra = wr * 64 + i * 16 + l15;
                int rb = wc * 64 + i * 16 + l15;
                int s = kk * 4 + l4;
                af[i][kk] = *reinterpret_cast<const f16x8*>(Ab + ra * 64 + ((s ^ (ra & 7)) << 3));
                bf[i][kk] = *reinterpret_cast<const f16x8*>(Bb + rb * 64 + ((s ^ (rb & 7)) << 3));
            }
#pragma unroll
        for (int i = 0; i < 4; ++i)
#pragma unroll
            for (int j = 0; j < 4; ++j)
#pragma unroll
                for (int kk = 0; kk < 2; ++kk)
                    acc[i][j] = __builtin_amdgcn_mfma_f32_16x16x32_f16(af[i][kk], bf[j][kk], acc[i][j], 0, 0, 0);
        __syncthreads();
        cur ^= 1;
    }
    // epilogue: LDS transpose -> coalesced f16x8 stores
    {
        f16* Es = lds;                   // view stride 132 f16 (bank spread)
#pragma unroll
        for (int i = 0; i < 4; ++i)
#pragma unroll
            for (int j = 0; j < 4; ++j) {
                int lc = wc * 64 + j * 16 + l15;
                float bb = biasAll[n0 + lc];
#pragma unroll
                for (int r = 0; r < 4; ++r) {
                    int lr = wr * 64 + i * 16 + l4 * 4 + r;
                    Es[lr * 132 + lc] = (f16)(acc[i][j][r] + bb);
                }
            }
        __syncthreads();
        const int rrow = t >> 4, slot = t & 15;
#pragma unroll
        for (int p2 = 0; p2 < 8; ++p2) {
            int r = p2 * 16 + rrow;
            *reinterpret_cast<f16x8*>(out + (size_t)(m0 + r) * 1536 + n0 + slot * 8) =
                *reinterpret_cast<const f16x8*>(Es + r * 132 + slot * 8);
        }
    }
}

// ---------------- attention ----------------
// One block per (bt,h). Reads fused qkv [M][1536]; writes ao f16 [M][512].

__global__ __launch_bounds__(256) void attn_kernel(const f16* __restrict__ qkv,
                                                   const float* __restrict__ maskb,
                                                   f16* __restrict__ ao) {
    __shared__ f16 Ks[256 * 64];         // XOR-swizzled [256][64]
    __shared__ f16 Vs[64 * 256];         // transposed V^T [dk][nf], key-swizzled
    __shared__ f16 Ps[4][16][264];
    const int t = threadIdx.x, wave = t >> 6, lane = t & 63;
    const int l15 = lane & 15, l4 = lane >> 4;
    const int bh = blockIdx.x, bt = bh >> 3, h = bh & 7;
    const int btq = bt * 256, hq = h * 64;
    const f16* qb = qkv + (size_t)btq * 1536 + hq;
    const f16* kb = qkv + (size_t)btq * 1536 + 512 + hq;
    const f16* vb = qkv + (size_t)btq * 1536 + 1024 + hq;

    stage_rows<256>(kb, 1536, 0, 0, Ks, wave, lane);
    {   // V transpose: coalesced f16x8 row reads -> swizzled scalar LDS writes
        const int slot = t & 7, r0 = t >> 3;
#pragma unroll
        for (int i = 0; i < 8; ++i) {
            int nf = r0 + i * 32;
            f16x8 v = *reinterpret_cast<const f16x8*>(vb + (size_t)nf * 1536 + slot * 8);
#pragma unroll
            for (int e = 0; e < 8; ++e) {
                int dk = slot * 8 + e;
                int key = (dk & 7) ^ (dk >> 3);
                Vs[dk * 256 + (((nf >> 3) ^ key) << 3) + (nf & 7)] = v[e];
            }
        }
    }
    __syncthreads();

    for (int s = 0; s < 4; ++s) {
        const int qrow_base = wave * 64 + s * 16;

        f16x8 aq[2];
#pragma unroll
        for (int kk = 0; kk < 2; ++kk)
            aq[kk] = *reinterpret_cast<const f16x8*>(
                qb + (size_t)(qrow_base + l15) * 1536 + kk * 32 + l4 * 8);

        f32x4 sacc[16];
#pragma unroll
        for (int ct = 0; ct < 16; ++ct) sacc[ct] = (f32x4){0.f, 0.f, 0.f, 0.f};
#pragma unroll
        for (int ct = 0; ct < 16; ++ct)
#pragma unroll
            for (int kk = 0; kk < 2; ++kk) {
                int rk = ct * 16 + l15;
                int sk = kk * 4 + l4;
                f16x8 bk_ = *reinterpret_cast<const f16x8*>(Ks + rk * 64 + ((sk ^ (rk & 7)) << 3));
                sacc[ct] = __builtin_amdgcn_mfma_f32_16x16x32_f16(aq[kk], bk_, sacc[ct], 0, 0, 0);
            }

        // mask + softmax: lane owns rows l4*4+r, col l15 of each 16-wide tile
#pragma unroll
        for (int r = 0; r < 4; ++r) {
            int ig = qrow_base + l4 * 4 + r;
            float mx = -1e38f;
#pragma unroll
            for (int ct = 0; ct < 16; ++ct) {
                float v = sacc[ct][r] + maskb[(size_t)ig * 256 + ct * 16 + l15];
                sacc[ct][r] = v;
                mx = fmaxf(mx, v);
            }
#pragma unroll
            for (int m = 1; m < 16; m <<= 1) mx = fmaxf(mx, __shfl_xor(mx, m, 64));
            float sum = 0.f;
#pragma unroll
            for (int ct = 0; ct < 16; ++ct) {
                float p = __expf(sacc[ct][r] - mx);
                sacc[ct][r] = p;
                sum += p;
            }
#pragma unroll
            for (int m = 1; m < 16; m <<= 1) sum += __shfl_xor(sum, m, 64);
            float rinv = 1.0f / sum;
#pragma unroll
            for (int ct = 0; ct < 16; ++ct)
                Ps[wave][l4 * 4 + r][ct * 16 + l15] = (f16)(sacc[ct][r] * rinv);
        }
        __syncthreads();

        // PV: out [16 rows][64 cols]
        f32x4 oacc[4] = {};
#pragma unroll
        for (int kk = 0; kk < 8; ++kk) {
            f16x8 ap = *reinterpret_cast<const f16x8*>(&Ps[wave][l15][kk * 32 + l4 * 8]);
#pragma unroll
            for (int c2 = 0; c2 < 4; ++c2) {
                int dk = c2 * 16 + l15;
                int key = (dk & 7) ^ (dk >> 3);
                int sv = kk * 4 + l4;
                f16x8 bv_ = *reinterpret_cast<const f16x8*>(Vs + dk * 256 + ((sv ^ key) << 3));
                oacc[c2] = __builtin_amdgcn_mfma_f32_16x16x32_f16(ap, bv_, oacc[c2], 0, 0, 0);
            }
        }
#pragma unroll
        for (int c2 = 0; c2 < 4; ++c2)
#pragma unroll
            for (int r = 0; r < 4; ++r) {
                int nf = qrow_base + l4 * 4 + r;
                int dcol = hq + c2 * 16 + l15;
                ao[((size_t)btq + nf) * 512 + dcol] = (f16)oacc[c2][r];
            }
        __syncthreads();
    }
}

// ---------------- output projection ----------------

__global__ __launch_bounds__(256) void o_gemm(const f16* __restrict__ A, const f16* __restrict__ W,
                                              const float* __restrict__ bo, float* __restrict__ out) {
    __shared__ f16 lds[32768];
    const int t = threadIdx.x, wave = t >> 6, lane = t & 63;
    const int l15 = lane & 15, l4 = lane >> 4;
    const int m0 = blockIdx.x * 128, n0 = blockIdx.y * 128;
    const int wr = wave >> 1, wc = wave & 1;
    f32x4 acc[4][4] = {};

    stage_rows<128>(A, 512, m0, 0, lds, wave, lane);
    stage_rows<128>(W, 512, n0, 0, lds + 8192, wave, lane);
    __syncthreads();
    int cur = 0;
    for (int kt = 0; kt < 8; ++kt) {
        if (kt < 7) {
            stage_rows<128>(A, 512, m0, (kt + 1) * 64, lds + (cur ^ 1) * 16384, wave, lane);
            stage_rows<128>(W, 512, n0, (kt + 1) * 64, lds + (cur ^ 1) * 16384 + 8192, wave, lane);
        }
        const f16* Ab = lds + cur * 16384;
        const f16* Bb = Ab + 8192;
        f16x8 af[4][2], bf[4][2];
#pragma unroll
        for (int i = 0; i < 4; ++i)
#pragma unroll
            for (int kk = 0; kk < 2; ++kk) {
                int ra = wr * 64 + i * 16 + l15;
                int rb = wc * 64 + i * 16 + l15;
                int s = kk * 4 + l4;
                af[i][kk] = *reinterpret_cast<const f16x8*>(Ab + ra * 64 + ((s ^ (ra & 7)) << 3));
                bf[i][kk] = *reinterpret_cast<const f16x8*>(Bb + rb * 64 + ((s ^ (rb & 7)) << 3));
            }
#pragma unroll
        for (int i = 0; i < 4; ++i)
#pragma unroll
            for (int j = 0; j < 4; ++j)
#pragma unroll
                for (int kk = 0; kk < 2; ++kk)
                    acc[i][j] = __builtin_amdgcn_mfma_f32_16x16x32_f16(af[i][kk], bf[j][kk], acc[i][j], 0, 0, 0);
        __syncthreads();
        cur ^= 1;
    }
#pragma unroll
    for (int i = 0; i < 4; ++i)
#pragma unroll
        for (int j = 0; j < 4; ++j) {
            int ng = n0 + wc * 64 + j * 16 + l15;
            float bb = bo[ng];
#pragma unroll
            for (int r = 0; r < 4; ++r) {
                int mg = m0 + wr * 64 + i * 16 + l4 * 4 + r;
                out[(size_t)mg * 512 + ng] = acc[i][j][r] + bb;
            }
        }
}

// ---------------- launch ----------------

extern "C" void kernel_launch(void* const* d_in, const int* in_sizes, int n_in,
                              void* d_out, int out_size, void* d_ws, size_t ws_size,
                              hipStream_t stream) {
    const float* x   = (const float*)d_in[0];
    const int*   adj = (const int*)d_in[1];
    const float* Wq  = (const float*)d_in[2];
    const float* bq  = (const float*)d_in[3];
    const float* Wk  = (const float*)d_in[4];
    const float* bk  = (const float*)d_in[5];
    const float* Wv  = (const float*)d_in[6];
    const float* bv  = (const float*)d_in[7];
    const float* Wo  = (const float*)d_in[8];
    const float* bo  = (const float*)d_in[9];
    float* out = (float*)d_out;

    char* ws = (char*)d_ws;
    f16*   Wh      = (f16*)ws;                                  // [1536][512]  1572864 B
    f16*   Woh     = (f16*)(ws + 1572864);                      // [512][512]    524288 B
    float* biasAll = (float*)(ws + 2097152);                    // [1536]          6144 B
    float* maskb   = (float*)(ws + 2103296);                    // [256][256]    262144 B
    f16*   xh      = (f16*)(ws + 2365440);                      // [M][512] f16, reused as ao
    f16*   qkvb    = (f16*)(ws + 2365440 + (size_t)M_ * 512 * 2); // [M][1536] f16
    f16*   aob     = xh;                                        // alias: xh dead after qkv_gemm

    cvt_x<<<2048, 256, 0, stream>>>(x, xh, M_ * 512 / 8);
    prep<<<512, 256, 0, stream>>>(Wq, Wk, Wv, Wo, bq, bk, bv, adj, Wh, Woh, biasAll, maskb);
    qkv_gemm<<<dim3(M_ / 128, 12), 256, 0, stream>>>(xh, Wh, biasAll, qkvb);
    attn_kernel<<<128 * H_, 256, 0, stream>>>(qkvb, maskb, aob);
    o_gemm<<<dim3(M_ / 128, 4), 256, 0, stream>>>(aob, Woh, bo, out);
}

// Round 3
// 204.136 us; speedup vs baseline: 1.2093x; 1.0969x over previous
//
#include <hip/hip_runtime.h>

#define NF 256
#define H_ 8
#define M_ 32768

typedef _Float16 f16;
typedef _Float16 f16x8 __attribute__((ext_vector_type(8)));
typedef float f32x4 __attribute__((ext_vector_type(4)));
typedef unsigned short u16x8 __attribute__((ext_vector_type(8)));

#define GLOAD16(src, dst) \
  __builtin_amdgcn_global_load_lds((const __attribute__((address_space(1))) void*)(src), \
                                   (__attribute__((address_space(3))) void*)(dst), 16, 0, 0)

// within-wave LDS fence: all outstanding ds ops complete, and no reordering across
#define LDS_FENCE() do { asm volatile("s_waitcnt lgkmcnt(0)" ::: "memory"); \
                         __builtin_amdgcn_sched_barrier(0); } while (0)

// Stage NR rows x 64 f16 into linear LDS [NR][64] with XOR-swizzle applied via the
// per-lane GLOBAL source column (rule 21: swizzle both sides or neither). 256 threads.
template <int NR>
__device__ __forceinline__ void stage_rows(const f16* __restrict__ g, int ld, int row0, int coff,
                                           f16* ldsb, int wave, int lane) {
    const int rr = wave * 8 + (lane >> 3);
    const int p  = lane & 7;
#pragma unroll
    for (int i = 0; i < NR / 32; ++i) {
        int r = i * 32 + rr;
        int col = ((p ^ (r & 7)) << 3);
        GLOAD16(g + (size_t)(row0 + r) * ld + coff + col, ldsb + (i * 32 + wave * 8) * 64);
    }
}

// same, 512 threads (8 waves): 64 rows per issue
template <int NR>
__device__ __forceinline__ void stage_rows512(const f16* __restrict__ g, int ld, int coff,
                                              f16* ldsb, int wave, int lane) {
    const int rr = wave * 8 + (lane >> 3);
    const int p  = lane & 7;
#pragma unroll
    for (int i = 0; i < NR / 64; ++i) {
        int r = i * 64 + rr;
        int col = ((p ^ (r & 7)) << 3);
        GLOAD16(g + (size_t)r * ld + coff + col, ldsb + (i * 64 + wave * 8) * 64);
    }
}

// ---------------- conversion / prep ----------------

__global__ void cvt_x(const float* __restrict__ src, f16* __restrict__ dst, int n8) {
    int idx = blockIdx.x * blockDim.x + threadIdx.x;
    int stride = gridDim.x * blockDim.x;
    for (; idx < n8; idx += stride) {
        const float4* s = reinterpret_cast<const float4*>(src + (size_t)idx * 8);
        float4 v0 = s[0], v1 = s[1];
        f16x8 o;
        o[0] = (f16)v0.x; o[1] = (f16)v0.y; o[2] = (f16)v0.z; o[3] = (f16)v0.w;
        o[4] = (f16)v1.x; o[5] = (f16)v1.y; o[6] = (f16)v1.z; o[7] = (f16)v1.w;
        *reinterpret_cast<f16x8*>(dst + (size_t)idx * 8) = o;
    }
}

#define QSCALE 0.1803368801111204f   // (1/8) * log2(e): exp2-domain scores

__global__ void prep(const float* __restrict__ Wq, const float* __restrict__ Wk,
                     const float* __restrict__ Wv, const float* __restrict__ Wo,
                     const float* __restrict__ bq, const float* __restrict__ bk,
                     const float* __restrict__ bv, const int* __restrict__ adj,
                     f16* __restrict__ Wh, f16* __restrict__ Woh,
                     float* __restrict__ biasAll, unsigned long long* __restrict__ bmask) {
    const int tid = blockIdx.x * 256 + threadIdx.x;   // grid = 512 blocks -> 131072 threads
    {
        const float* s; f16* d; float sc = 1.0f;
        int pp = tid >> 15, off = tid & 32767;
        if (pp == 0)      { s = Wq; d = Wh;              sc = QSCALE; }
        else if (pp == 1) { s = Wk; d = Wh + 512 * 512; }
        else if (pp == 2) { s = Wv; d = Wh + 2 * 512 * 512; }
        else              { s = Wo; d = Woh; }
        const float4* sv4 = reinterpret_cast<const float4*>(s + (size_t)off * 8);
        float4 v0 = sv4[0], v1 = sv4[1];
        f16x8 o;
        o[0] = (f16)(v0.x * sc); o[1] = (f16)(v0.y * sc);
        o[2] = (f16)(v0.z * sc); o[3] = (f16)(v0.w * sc);
        o[4] = (f16)(v1.x * sc); o[5] = (f16)(v1.y * sc);
        o[6] = (f16)(v1.z * sc); o[7] = (f16)(v1.w * sc);
        *reinterpret_cast<f16x8*>(d + (size_t)off * 8) = o;
    }
    if (tid < 1536) {
        float v = (tid < 512) ? QSCALE * bq[tid] : (tid < 1024) ? bk[tid - 512] : bv[tid - 1024];
        biasAll[tid] = v;
    }
    if (tid < 65536) {   // 65536 % 64 == 0: whole waves in-branch, full exec for ballot
        unsigned long long bal = __ballot(adj[tid] > 0);
        if ((tid & 63) == 0) bmask[tid >> 6] = bal;
    }
}

// ---------------- fused QKV GEMM ----------------
// A = xh [M][512] f16, W = [1536][512] f16 (QSCALE*Wq | Wk | Wv rows).
// out = qkv [M][1536] f16 row-major.  128x128 tile, BK=64, 2-phase dbuf gload_lds.

__global__ __launch_bounds__(256) void qkv_gemm(const f16* __restrict__ A, const f16* __restrict__ W,
                                                const float* __restrict__ biasAll,
                                                f16* __restrict__ out) {
    __shared__ f16 lds[32768];           // 2 bufs x (A 8192 + B 8192)
    const int t = threadIdx.x, wave = t >> 6, lane = t & 63;
    const int l15 = lane & 15, l4 = lane >> 4;
    const int m0 = blockIdx.x * 128, n0 = blockIdx.y * 128;
    const int wr = wave >> 1, wc = wave & 1;
    f32x4 acc[4][4] = {};

    stage_rows<128>(A, 512, m0, 0, lds, wave, lane);
    stage_rows<128>(W, 512, n0, 0, lds + 8192, wave, lane);
    __syncthreads();
    int cur = 0;
    for (int kt = 0; kt < 8; ++kt) {
        if (kt < 7) {
            stage_rows<128>(A, 512, m0, (kt + 1) * 64, lds + (cur ^ 1) * 16384, wave, lane);
            stage_rows<128>(W, 512, n0, (kt + 1) * 64, lds + (cur ^ 1) * 16384 + 8192, wave, lane);
        }
        const f16* Ab = lds + cur * 16384;
        const f16* Bb = Ab + 8192;
        f16x8 af[4][2], bf[4][2];
#pragma unroll
        for (int i = 0; i < 4; ++i)
#pragma unroll
            for (int kk = 0; kk < 2; ++kk) {
                int ra = wr * 64 + i * 16 + l15;
                int rb = wc * 64 + i * 16 + l15;
                int s = kk * 4 + l4;
                af[i][kk] = *reinterpret_cast<const f16x8*>(Ab + ra * 64 + ((s ^ (ra & 7)) << 3));
                bf[i][kk] = *reinterpret_cast<const f16x8*>(Bb + rb * 64 + ((s ^ (rb & 7)) << 3));
            }
#pragma unroll
        for (int i = 0; i < 4; ++i)
#pragma unroll
            for (int j = 0; j < 4; ++j)
#pragma unroll
                for (int kk = 0; kk < 2; ++kk)
                    acc[i][j] = __builtin_amdgcn_mfma_f32_16x16x32_f16(af[i][kk], bf[j][kk], acc[i][j], 0, 0, 0);
        __syncthreads();
        cur ^= 1;
    }
    // epilogue: LDS transpose -> coalesced f16x8 stores
    {
        f16* Es = lds;                   // view stride 132 f16 (bank spread)
#pragma unroll
        for (int i = 0; i < 4; ++i)
#pragma unroll
            for (int j = 0; j < 4; ++j) {
                int lc = wc * 64 + j * 16 + l15;
                float bb = biasAll[n0 + lc];
#pragma unroll
                for (int r = 0; r < 4; ++r) {
                    int lr = wr * 64 + i * 16 + l4 * 4 + r;
                    Es[lr * 132 + lc] = (f16)(acc[i][j][r] + bb);
                }
            }
        __syncthreads();
        const int rrow = t >> 4, slot = t & 15;
#pragma unroll
        for (int p2 = 0; p2 < 8; ++p2) {
            int r = p2 * 16 + rrow;
            *reinterpret_cast<f16x8*>(out + (size_t)(m0 + r) * 1536 + n0 + slot * 8) =
                *reinterpret_cast<const f16x8*>(Es + r * 132 + slot * 8);
        }
    }
}

// ---------------- attention ----------------
// One block (512 thr, 8 waves) per (bt,h). Wave w owns rows w*32..w*32+31 (2 strips).
// No per-strip barriers: Ps is per-wave; Ks/Vs read-only after the single stage sync.

__global__ __launch_bounds__(512) void attn_kernel(const f16* __restrict__ qkv,
                                                   const unsigned long long* __restrict__ bmg,
                                                   f16* __restrict__ ao) {
    __shared__ f16 Ks[256 * 64];                 // XOR-swizzled [256][64]
    __shared__ f16 Vs[64 * 256];                 // transposed V^T [dk][nf], key-swizzled
    __shared__ f16 Ps[8][16][264];               // per-wave P strip (unnormalized)
    __shared__ unsigned long long BMs[1024];     // bitmask u64[256][4] == u16[256][16]
    const int t = threadIdx.x, wave = t >> 6, lane = t & 63;
    const int l15 = lane & 15, l4 = lane >> 4;
    const int bh = blockIdx.x, bt = bh >> 3, h = bh & 7;
    const int btq = bt * 256, hq = h * 64;
    const f16* qb = qkv + (size_t)btq * 1536 + hq;
    const f16* kb = qkv + (size_t)btq * 1536 + 512 + hq;
    const f16* vb = qkv + (size_t)btq * 1536 + 1024 + hq;

    stage_rows512<256>(kb, 1536, 0, Ks, wave, lane);
    GLOAD16((const char*)bmg + (size_t)t * 16, (char*)(BMs + wave * 128));
    {   // V transpose: coalesced f16x8 row reads -> swizzled scalar LDS writes
        const int slot = t & 7, r0 = t >> 3;     // r0 in 0..63
#pragma unroll
        for (int i = 0; i < 4; ++i) {
            int nf = r0 + i * 64;
            f16x8 v = *reinterpret_cast<const f16x8*>(vb + (size_t)nf * 1536 + slot * 8);
#pragma unroll
            for (int e = 0; e < 8; ++e) {
                int dk = slot * 8 + e;
                int key = (dk & 7) ^ (dk >> 3);
                Vs[dk * 256 + (((nf >> 3) ^ key) << 3) + (nf & 7)] = v[e];
            }
        }
    }
    __syncthreads();

    for (int s = 0; s < 2; ++s) {
        const int qrow_base = wave * 32 + s * 16;

        f16x8 aq[2];
#pragma unroll
        for (int kk = 0; kk < 2; ++kk)
            aq[kk] = *reinterpret_cast<const f16x8*>(
                qb + (size_t)(qrow_base + l15) * 1536 + kk * 32 + l4 * 8);

        f32x4 sacc[16];
#pragma unroll
        for (int ct = 0; ct < 16; ++ct) sacc[ct] = (f32x4){0.f, 0.f, 0.f, 0.f};
#pragma unroll
        for (int ct = 0; ct < 16; ++ct)
#pragma unroll
            for (int kk = 0; kk < 2; ++kk) {
                int rk = ct * 16 + l15;
                int sk = kk * 4 + l4;
                f16x8 bk_ = *reinterpret_cast<const f16x8*>(Ks + rk * 64 + ((sk ^ (rk & 7)) << 3));
                sacc[ct] = __builtin_amdgcn_mfma_f32_16x16x32_f16(aq[kk], bk_, sacc[ct], 0, 0, 0);
            }

        LDS_FENCE();   // WAR: prev strip's PV reads of Ps[wave] must complete before rewrite

        // softmax (exp2 domain). Max over raw scores (shift-invariance: p<=1 regardless);
        // mask applied as a select on p. lane owns rows l4*4+r, col l15 of each 16-tile.
        float rs[4];
#pragma unroll
        for (int r = 0; r < 4; ++r) {
            const int ig = qrow_base + l4 * 4 + r;
            const u16x8* mr = reinterpret_cast<const u16x8*>(BMs + ig * 4);
            u16x8 w0 = mr[0], w1 = mr[1];
            float mx = -1e38f;
#pragma unroll
            for (int ct = 0; ct < 16; ++ct) mx = fmaxf(mx, sacc[ct][r]);
#pragma unroll
            for (int m = 1; m < 16; m <<= 1) mx = fmaxf(mx, __shfl_xor(mx, m, 64));
            float sum = 0.f;
#pragma unroll
            for (int ct = 0; ct < 16; ++ct) {
                unsigned wbit = (ct < 8) ? (unsigned)w0[ct] : (unsigned)w1[ct & 7];
                float p = __builtin_exp2f(sacc[ct][r] - mx);
                p = ((wbit >> l15) & 1u) ? p : 0.0f;
                sacc[ct][r] = p;
                sum += p;
            }
#pragma unroll
            for (int m = 1; m < 16; m <<= 1) sum += __shfl_xor(sum, m, 64);
            rs[r] = 1.0f / sum;
#pragma unroll
            for (int ct = 0; ct < 16; ++ct)
                Ps[wave][l4 * 4 + r][ct * 16 + l15] = (f16)sacc[ct][r];
        }

        LDS_FENCE();   // RAW: Ps writes visible to all lanes of this wave before PV reads

        // PV: out [16 rows][64 cols], normalization deferred to oacc scale
        f32x4 oacc[4] = {};
#pragma unroll
        for (int kk = 0; kk < 8; ++kk) {
            f16x8 ap = *reinterpret_cast<const f16x8*>(&Ps[wave][l15][kk * 32 + l4 * 8]);
#pragma unroll
            for (int c2 = 0; c2 < 4; ++c2) {
                int dk = c2 * 16 + l15;
                int key = (dk & 7) ^ (dk >> 3);
                int sv = kk * 4 + l4;
                f16x8 bv_ = *reinterpret_cast<const f16x8*>(Vs + dk * 256 + ((sv ^ key) << 3));
                oacc[c2] = __builtin_amdgcn_mfma_f32_16x16x32_f16(ap, bv_, oacc[c2], 0, 0, 0);
            }
        }
#pragma unroll
        for (int c2 = 0; c2 < 4; ++c2)
#pragma unroll
            for (int r = 0; r < 4; ++r) {
                int nf = qrow_base + l4 * 4 + r;
                int dcol = hq + c2 * 16 + l15;
                ao[((size_t)btq + nf) * 512 + dcol] = (f16)(oacc[c2][r] * rs[r]);
            }
    }
}

// ---------------- output projection ----------------

__global__ __launch_bounds__(256) void o_gemm(const f16* __restrict__ A, const f16* __restrict__ W,
                                              const float* __restrict__ bo, float* __restrict__ out) {
    __shared__ f16 lds[32768];
    const int t = threadIdx.x, wave = t >> 6, lane = t & 63;
    const int l15 = lane & 15, l4 = lane >> 4;
    const int m0 = blockIdx.x * 128, n0 = blockIdx.y * 128;
    const int wr = wave >> 1, wc = wave & 1;
    f32x4 acc[4][4] = {};

    stage_rows<128>(A, 512, m0, 0, lds, wave, lane);
    stage_rows<128>(W, 512, n0, 0, lds + 8192, wave, lane);
    __syncthreads();
    int cur = 0;
    for (int kt = 0; kt < 8; ++kt) {
        if (kt < 7) {
            stage_rows<128>(A, 512, m0, (kt + 1) * 64, lds + (cur ^ 1) * 16384, wave, lane);
            stage_rows<128>(W, 512, n0, (kt + 1) * 64, lds + (cur ^ 1) * 16384 + 8192, wave, lane);
        }
        const f16* Ab = lds + cur * 16384;
        const f16* Bb = Ab + 8192;
        f16x8 af[4][2], bf[4][2];
#pragma unroll
        for (int i = 0; i < 4; ++i)
#pragma unroll
            for (int kk = 0; kk < 2; ++kk) {
                int ra = wr * 64 + i * 16 + l15;
                int rb = wc * 64 + i * 16 + l15;
                int s = kk * 4 + l4;
                af[i][kk] = *reinterpret_cast<const f16x8*>(Ab + ra * 64 + ((s ^ (ra & 7)) << 3));
                bf[i][kk] = *reinterpret_cast<const f16x8*>(Bb + rb * 64 + ((s ^ (rb & 7)) << 3));
            }
#pragma unroll
        for (int i = 0; i < 4; ++i)
#pragma unroll
            for (int j = 0; j < 4; ++j)
#pragma unroll
                for (int kk = 0; kk < 2; ++kk)
                    acc[i][j] = __builtin_amdgcn_mfma_f32_16x16x32_f16(af[i][kk], bf[j][kk], acc[i][j], 0, 0, 0);
        __syncthreads();
        cur ^= 1;
    }
#pragma unroll
    for (int i = 0; i < 4; ++i)
#pragma unroll
        for (int j = 0; j < 4; ++j) {
            int ng = n0 + wc * 64 + j * 16 + l15;
            float bb = bo[ng];
#pragma unroll
            for (int r = 0; r < 4; ++r) {
                int mg = m0 + wr * 64 + i * 16 + l4 * 4 + r;
                out[(size_t)mg * 512 + ng] = acc[i][j][r] + bb;
            }
        }
}

// ---------------- launch ----------------

extern "C" void kernel_launch(void* const* d_in, const int* in_sizes, int n_in,
                              void* d_out, int out_size, void* d_ws, size_t ws_size,
                              hipStream_t stream) {
    const float* x   = (const float*)d_in[0];
    const int*   adj = (const int*)d_in[1];
    const float* Wq  = (const float*)d_in[2];
    const float* bq  = (const float*)d_in[3];
    const float* Wk  = (const float*)d_in[4];
    const float* bk  = (const float*)d_in[5];
    const float* Wv  = (const float*)d_in[6];
    const float* bv  = (const float*)d_in[7];
    const float* Wo  = (const float*)d_in[8];
    const float* bo  = (const float*)d_in[9];
    float* out = (float*)d_out;

    char* ws = (char*)d_ws;
    f16*   Wh      = (f16*)ws;                                  // [1536][512]  1572864 B
    f16*   Woh     = (f16*)(ws + 1572864);                      // [512][512]    524288 B
    float* biasAll = (float*)(ws + 2097152);                    // [1536]          6144 B
    unsigned long long* bmask = (unsigned long long*)(ws + 2103296); // [1024]     8192 B
    f16*   xh      = (f16*)(ws + 2111488);                      // [M][512] f16, reused as ao
    f16*   qkvb    = (f16*)(ws + 2111488 + (size_t)M_ * 512 * 2); // [M][1536] f16
    f16*   aob     = xh;                                        // alias: xh dead after qkv_gemm

    cvt_x<<<2048, 256, 0, stream>>>(x, xh, M_ * 512 / 8);
    prep<<<512, 256, 0, stream>>>(Wq, Wk, Wv, Wo, bq, bk, bv, adj, Wh, Woh, biasAll, bmask);
    qkv_gemm<<<dim3(M_ / 128, 12), 256, 0, stream>>>(xh, Wh, biasAll, qkvb);
    attn_kernel<<<128 * H_, 512, 0, stream>>>(qkvb, bmask, aob);
    o_gemm<<<dim3(M_ / 128, 4), 256, 0, stream>>>(aob, Woh, bo, out);
}

// Round 4
// 190.796 us; speedup vs baseline: 1.2938x; 1.0699x over previous
//
#include <hip/hip_runtime.h>

#define NF 256
#define H_ 8
#define M_ 32768

typedef _Float16 f16;
typedef _Float16 f16x8 __attribute__((ext_vector_type(8)));
typedef float f32x4 __attribute__((ext_vector_type(4)));
typedef unsigned short u16x8 __attribute__((ext_vector_type(8)));

#define GLOAD16(src, dst) \
  __builtin_amdgcn_global_load_lds((const __attribute__((address_space(1))) void*)(src), \
                                   (__attribute__((address_space(3))) void*)(dst), 16, 0, 0)

// within-wave LDS fence: all outstanding ds ops complete, and no reordering across
#define LDS_FENCE() do { asm volatile("s_waitcnt lgkmcnt(0)" ::: "memory"); \
                         __builtin_amdgcn_sched_barrier(0); } while (0)

// ---- BK=32 staging: NR rows x 32 f16 into linear LDS [NR][32].
// Swizzle: lds slot p of row r holds global slot p ^ ((r>>1)&3)  (self-inverse;
// applied on the GLOBAL source col — rule 21). Even/odd rows tile the 128B bank
// space -> worst 2-way aliasing (free, m136).
template <int NR>
__device__ __forceinline__ void stage32(const f16* __restrict__ g, int ld, int row0, int coff,
                                        f16* ldsb, int wave, int lane) {
    const int rr = wave * 16 + (lane >> 2);
    const int p  = lane & 3;
#pragma unroll
    for (int i = 0; i < NR / 64; ++i) {
        int r = i * 64 + rr;
        int col = ((p ^ ((r >> 1) & 3)) << 3);
        GLOAD16(g + (size_t)(row0 + r) * ld + coff + col, ldsb + (i * 64 + wave * 16) * 32);
    }
}

// ---- BK=64 staging (attn K-stage), 512 threads (8 waves)
template <int NR>
__device__ __forceinline__ void stage_rows512(const f16* __restrict__ g, int ld, int coff,
                                              f16* ldsb, int wave, int lane) {
    const int rr = wave * 8 + (lane >> 3);
    const int p  = lane & 7;
#pragma unroll
    for (int i = 0; i < NR / 64; ++i) {
        int r = i * 64 + rr;
        int col = ((p ^ (r & 7)) << 3);
        GLOAD16(g + (size_t)r * ld + coff + col, ldsb + (i * 64 + wave * 8) * 64);
    }
}

// ---------------- conversion / prep ----------------

__global__ void cvt_x(const float* __restrict__ src, f16* __restrict__ dst, int n8) {
    int idx = blockIdx.x * blockDim.x + threadIdx.x;
    int stride = gridDim.x * blockDim.x;
    for (; idx < n8; idx += stride) {
        const float4* s = reinterpret_cast<const float4*>(src + (size_t)idx * 8);
        float4 v0 = s[0], v1 = s[1];
        f16x8 o;
        o[0] = (f16)v0.x; o[1] = (f16)v0.y; o[2] = (f16)v0.z; o[3] = (f16)v0.w;
        o[4] = (f16)v1.x; o[5] = (f16)v1.y; o[6] = (f16)v1.z; o[7] = (f16)v1.w;
        *reinterpret_cast<f16x8*>(dst + (size_t)idx * 8) = o;
    }
}

#define QSCALE 0.1803368801111204f   // (1/8) * log2(e): exp2-domain scores

__global__ void prep(const float* __restrict__ Wq, const float* __restrict__ Wk,
                     const float* __restrict__ Wv, const float* __restrict__ Wo,
                     const float* __restrict__ bq, const float* __restrict__ bk,
                     const float* __restrict__ bv, const int* __restrict__ adj,
                     f16* __restrict__ Wh, f16* __restrict__ Woh,
                     float* __restrict__ biasAll, unsigned long long* __restrict__ bmask) {
    const int tid = blockIdx.x * 256 + threadIdx.x;   // grid = 512 blocks -> 131072 threads
    {
        const float* s; f16* d; float sc = 1.0f;
        int pp = tid >> 15, off = tid & 32767;
        if (pp == 0)      { s = Wq; d = Wh;              sc = QSCALE; }
        else if (pp == 1) { s = Wk; d = Wh + 512 * 512; }
        else if (pp == 2) { s = Wv; d = Wh + 2 * 512 * 512; }
        else              { s = Wo; d = Woh; }
        const float4* sv4 = reinterpret_cast<const float4*>(s + (size_t)off * 8);
        float4 v0 = sv4[0], v1 = sv4[1];
        f16x8 o;
        o[0] = (f16)(v0.x * sc); o[1] = (f16)(v0.y * sc);
        o[2] = (f16)(v0.z * sc); o[3] = (f16)(v0.w * sc);
        o[4] = (f16)(v1.x * sc); o[5] = (f16)(v1.y * sc);
        o[6] = (f16)(v1.z * sc); o[7] = (f16)(v1.w * sc);
        *reinterpret_cast<f16x8*>(d + (size_t)off * 8) = o;
    }
    if (tid < 1536) {
        float v = (tid < 512) ? QSCALE * bq[tid] : (tid < 1024) ? bk[tid - 512] : bv[tid - 1024];
        biasAll[tid] = v;
    }
    if (tid < 65536) {   // 65536 % 64 == 0: whole waves in-branch, full exec for ballot
        unsigned long long bal = __ballot(adj[tid] > 0);
        if ((tid & 63) == 0) bmask[tid >> 6] = bal;
    }
}

// ---------------- fused QKV GEMM ----------------
// A = xh [M][512] f16, W = [1536][512] f16 (QSCALE*Wq | Wk | Wv rows).
// out = qkv [M][1536] f16 row-major.  128x128 tile, BK=32, 2-phase dbuf gload_lds,
// XCD-chunked linear grid: per XCD, the 12 n-tiles of one m-tile run co-temporally.

__global__ __launch_bounds__(256) void qkv_gemm(const f16* __restrict__ A, const f16* __restrict__ W,
                                                const float* __restrict__ biasAll,
                                                f16* __restrict__ out) {
    __shared__ union { f16 stage[16384]; f16 epi[128 * 132]; } u;   // 33792 B -> 4 blk/CU
    const int t = threadIdx.x, wave = t >> 6, lane = t & 63;
    const int l15 = lane & 15, l4 = lane >> 4;
    const int lb = blockIdx.x;                 // 3072 linear blocks
    const int xcd = lb & 7, idx = lb >> 3;     // 384 per XCD = 32 m-tiles x 12 n-tiles
    const int m0 = (xcd * 32 + idx / 12) * 128;
    const int n0 = (idx % 12) * 128;
    const int wr = wave >> 1, wc = wave & 1;
    f32x4 acc[4][4] = {};

    stage32<128>(A, 512, m0, 0, u.stage, wave, lane);
    stage32<128>(W, 512, n0, 0, u.stage + 4096, wave, lane);
    __syncthreads();
    int cur = 0;
    for (int kt = 0; kt < 16; ++kt) {
        if (kt < 15) {
            stage32<128>(A, 512, m0, (kt + 1) * 32, u.stage + (cur ^ 1) * 8192, wave, lane);
            stage32<128>(W, 512, n0, (kt + 1) * 32, u.stage + (cur ^ 1) * 8192 + 4096, wave, lane);
        }
        const f16* Ab = u.stage + cur * 8192;
        const f16* Bb = Ab + 4096;
        f16x8 af[4], bf[4];
#pragma unroll
        for (int i = 0; i < 4; ++i) {
            int ra = wr * 64 + i * 16 + l15;
            af[i] = *reinterpret_cast<const f16x8*>(Ab + ra * 32 + ((l4 ^ ((ra >> 1) & 3)) << 3));
        }
#pragma unroll
        for (int j = 0; j < 4; ++j) {
            int rb = wc * 64 + j * 16 + l15;
            bf[j] = *reinterpret_cast<const f16x8*>(Bb + rb * 32 + ((l4 ^ ((rb >> 1) & 3)) << 3));
        }
#pragma unroll
        for (int i = 0; i < 4; ++i)
#pragma unroll
            for (int j = 0; j < 4; ++j)
                acc[i][j] = __builtin_amdgcn_mfma_f32_16x16x32_f16(af[i], bf[j], acc[i][j], 0, 0, 0);
        __syncthreads();
        cur ^= 1;
    }
    // epilogue: LDS transpose -> coalesced f16x8 stores
    {
        f16* Es = u.epi;                 // stride 132 f16 (bank spread)
#pragma unroll
        for (int i = 0; i < 4; ++i)
#pragma unroll
            for (int j = 0; j < 4; ++j) {
                int lc = wc * 64 + j * 16 + l15;
                float bb = biasAll[n0 + lc];
#pragma unroll
                for (int r = 0; r < 4; ++r) {
                    int lr = wr * 64 + i * 16 + l4 * 4 + r;
                    Es[lr * 132 + lc] = (f16)(acc[i][j][r] + bb);
                }
            }
        __syncthreads();
        const int rrow = t >> 4, slot = t & 15;
#pragma unroll
        for (int p2 = 0; p2 < 8; ++p2) {
            int r = p2 * 16 + rrow;
            *reinterpret_cast<f16x8*>(out + (size_t)(m0 + r) * 1536 + n0 + slot * 8) =
                *reinterpret_cast<const f16x8*>(Es + r * 132 + slot * 8);
        }
    }
}

// ---------------- attention ----------------
// One block (512 thr, 8 waves) per (bt,h). Wave w owns rows w*32..w*32+31 (2 strips).
// No per-strip barriers: Ps is per-wave; Ks/Vs read-only after the single stage sync.

__global__ __launch_bounds__(512) void attn_kernel(const f16* __restrict__ qkv,
                                                   const unsigned long long* __restrict__ bmg,
                                                   f16* __restrict__ ao) {
    __shared__ f16 Ks[256 * 64];                 // XOR-swizzled [256][64]
    __shared__ f16 Vs[64 * 256];                 // transposed V^T [dk][nf], key-swizzled
    __shared__ f16 Ps[8][16][264];               // per-wave P strip (unnormalized)
    __shared__ unsigned long long BMs[1024];     // bitmask u64[256][4] == u16[256][16]
    const int t = threadIdx.x, wave = t >> 6, lane = t & 63;
    const int l15 = lane & 15, l4 = lane >> 4;
    const int bh = blockIdx.x, bt = bh >> 3, h = bh & 7;
    const int btq = bt * 256, hq = h * 64;
    const f16* qb = qkv + (size_t)btq * 1536 + hq;
    const f16* kb = qkv + (size_t)btq * 1536 + 512 + hq;
    const f16* vb = qkv + (size_t)btq * 1536 + 1024 + hq;

    stage_rows512<256>(kb, 1536, 0, Ks, wave, lane);
    GLOAD16((const char*)bmg + (size_t)t * 16, (char*)(BMs + wave * 128));
    {   // V transpose: coalesced f16x8 row reads -> swizzled scalar LDS writes
        const int slot = t & 7, r0 = t >> 3;     // r0 in 0..63
#pragma unroll
        for (int i = 0; i < 4; ++i) {
            int nf = r0 + i * 64;
            f16x8 v = *reinterpret_cast<const f16x8*>(vb + (size_t)nf * 1536 + slot * 8);
#pragma unroll
            for (int e = 0; e < 8; ++e) {
                int dk = slot * 8 + e;
                int key = (dk & 7) ^ (dk >> 3);
                Vs[dk * 256 + (((nf >> 3) ^ key) << 3) + (nf & 7)] = v[e];
            }
        }
    }
    __syncthreads();

    for (int s = 0; s < 2; ++s) {
        const int qrow_base = wave * 32 + s * 16;

        f16x8 aq[2];
#pragma unroll
        for (int kk = 0; kk < 2; ++kk)
            aq[kk] = *reinterpret_cast<const f16x8*>(
                qb + (size_t)(qrow_base + l15) * 1536 + kk * 32 + l4 * 8);

        f32x4 sacc[16];
#pragma unroll
        for (int ct = 0; ct < 16; ++ct) sacc[ct] = (f32x4){0.f, 0.f, 0.f, 0.f};
#pragma unroll
        for (int ct = 0; ct < 16; ++ct)
#pragma unroll
            for (int kk = 0; kk < 2; ++kk) {
                int rk = ct * 16 + l15;
                int sk = kk * 4 + l4;
                f16x8 bk_ = *reinterpret_cast<const f16x8*>(Ks + rk * 64 + ((sk ^ (rk & 7)) << 3));
                sacc[ct] = __builtin_amdgcn_mfma_f32_16x16x32_f16(aq[kk], bk_, sacc[ct], 0, 0, 0);
            }

        LDS_FENCE();   // WAR: prev strip's PV reads of Ps[wave] must complete before rewrite

        // softmax (exp2 domain). Max over raw scores (shift-invariance: p<=1 regardless);
        // mask applied as a select on p. lane owns rows l4*4+r, col l15 of each 16-tile.
        float rs[4];
#pragma unroll
        for (int r = 0; r < 4; ++r) {
            const int ig = qrow_base + l4 * 4 + r;
            const u16x8* mr = reinterpret_cast<const u16x8*>(BMs + ig * 4);
            u16x8 w0 = mr[0], w1 = mr[1];
            float mx = -1e38f;
#pragma unroll
            for (int ct = 0; ct < 16; ++ct) mx = fmaxf(mx, sacc[ct][r]);
#pragma unroll
            for (int m = 1; m < 16; m <<= 1) mx = fmaxf(mx, __shfl_xor(mx, m, 64));
            float sum = 0.f;
#pragma unroll
            for (int ct = 0; ct < 16; ++ct) {
                unsigned wbit = (ct < 8) ? (unsigned)w0[ct] : (unsigned)w1[ct & 7];
                float p = __builtin_exp2f(sacc[ct][r] - mx);
                p = ((wbit >> l15) & 1u) ? p : 0.0f;
                sacc[ct][r] = p;
                sum += p;
            }
#pragma unroll
            for (int m = 1; m < 16; m <<= 1) sum += __shfl_xor(sum, m, 64);
            rs[r] = 1.0f / sum;
#pragma unroll
            for (int ct = 0; ct < 16; ++ct)
                Ps[wave][l4 * 4 + r][ct * 16 + l15] = (f16)sacc[ct][r];
        }

        LDS_FENCE();   // RAW: Ps writes visible to all lanes of this wave before PV reads

        // PV: out [16 rows][64 cols], normalization deferred to oacc scale
        f32x4 oacc[4] = {};
#pragma unroll
        for (int kk = 0; kk < 8; ++kk) {
            f16x8 ap = *reinterpret_cast<const f16x8*>(&Ps[wave][l15][kk * 32 + l4 * 8]);
#pragma unroll
            for (int c2 = 0; c2 < 4; ++c2) {
                int dk = c2 * 16 + l15;
                int key = (dk & 7) ^ (dk >> 3);
                int sv = kk * 4 + l4;
                f16x8 bv_ = *reinterpret_cast<const f16x8*>(Vs + dk * 256 + ((sv ^ key) << 3));
                oacc[c2] = __builtin_amdgcn_mfma_f32_16x16x32_f16(ap, bv_, oacc[c2], 0, 0, 0);
            }
        }
#pragma unroll
        for (int c2 = 0; c2 < 4; ++c2)
#pragma unroll
            for (int r = 0; r < 4; ++r) {
                int nf = qrow_base + l4 * 4 + r;
                int dcol = hq + c2 * 16 + l15;
                ao[((size_t)btq + nf) * 512 + dcol] = (f16)(oacc[c2][r] * rs[r]);
            }
    }
}

// ---------------- output projection ----------------
// 128x128 tile, BK=32, XCD-chunked linear grid (1024 blocks: 32 m-tiles x 4 n-tiles per XCD).

__global__ __launch_bounds__(256) void o_gemm(const f16* __restrict__ A, const f16* __restrict__ W,
                                              const float* __restrict__ bo, float* __restrict__ out) {
    __shared__ f16 lds[16384];                 // 32 KB -> 5 blk/CU
    const int t = threadIdx.x, wave = t >> 6, lane = t & 63;
    const int l15 = lane & 15, l4 = lane >> 4;
    const int lb = blockIdx.x;
    const int xcd = lb & 7, idx = lb >> 3;     // 128 per XCD = 32 m-tiles x 4 n-tiles
    const int m0 = (xcd * 32 + idx / 4) * 128;
    const int n0 = (idx % 4) * 128;
    const int wr = wave >> 1, wc = wave & 1;
    f32x4 acc[4][4] = {};

    stage32<128>(A, 512, m0, 0, lds, wave, lane);
    stage32<128>(W, 512, n0, 0, lds + 4096, wave, lane);
    __syncthreads();
    int cur = 0;
    for (int kt = 0; kt < 16; ++kt) {
        if (kt < 15) {
            stage32<128>(A, 512, m0, (kt + 1) * 32, lds + (cur ^ 1) * 8192, wave, lane);
            stage32<128>(W, 512, n0, (kt + 1) * 32, lds + (cur ^ 1) * 8192 + 4096, wave, lane);
        }
        const f16* Ab = lds + cur * 8192;
        const f16* Bb = Ab + 4096;
        f16x8 af[4], bf[4];
#pragma unroll
        for (int i = 0; i < 4; ++i) {
            int ra = wr * 64 + i * 16 + l15;
            af[i] = *reinterpret_cast<const f16x8*>(Ab + ra * 32 + ((l4 ^ ((ra >> 1) & 3)) << 3));
        }
#pragma unroll
        for (int j = 0; j < 4; ++j) {
            int rb = wc * 64 + j * 16 + l15;
            bf[j] = *reinterpret_cast<const f16x8*>(Bb + rb * 32 + ((l4 ^ ((rb >> 1) & 3)) << 3));
        }
#pragma unroll
        for (int i = 0; i < 4; ++i)
#pragma unroll
            for (int j = 0; j < 4; ++j)
                acc[i][j] = __builtin_amdgcn_mfma_f32_16x16x32_f16(af[i], bf[j], acc[i][j], 0, 0, 0);
        __syncthreads();
        cur ^= 1;
    }
#pragma unroll
    for (int i = 0; i < 4; ++i)
#pragma unroll
        for (int j = 0; j < 4; ++j) {
            int ng = n0 + wc * 64 + j * 16 + l15;
            float bb = bo[ng];
#pragma unroll
            for (int r = 0; r < 4; ++r) {
                int mg = m0 + wr * 64 + i * 16 + l4 * 4 + r;
                out[(size_t)mg * 512 + ng] = acc[i][j][r] + bb;
            }
        }
}

// ---------------- launch ----------------

extern "C" void kernel_launch(void* const* d_in, const int* in_sizes, int n_in,
                              void* d_out, int out_size, void* d_ws, size_t ws_size,
                              hipStream_t stream) {
    const float* x   = (const float*)d_in[0];
    const int*   adj = (const int*)d_in[1];
    const float* Wq  = (const float*)d_in[2];
    const float* bq  = (const float*)d_in[3];
    const float* Wk  = (const float*)d_in[4];
    const float* bk  = (const float*)d_in[5];
    const float* Wv  = (const float*)d_in[6];
    const float* bv  = (const float*)d_in[7];
    const float* Wo  = (const float*)d_in[8];
    const float* bo  = (const float*)d_in[9];
    float* out = (float*)d_out;

    char* ws = (char*)d_ws;
    f16*   Wh      = (f16*)ws;                                  // [1536][512]  1572864 B
    f16*   Woh     = (f16*)(ws + 1572864);                      // [512][512]    524288 B
    float* biasAll = (float*)(ws + 2097152);                    // [1536]          6144 B
    unsigned long long* bmask = (unsigned long long*)(ws + 2103296); // [1024]     8192 B
    f16*   xh      = (f16*)(ws + 2111488);                      // [M][512] f16, reused as ao
    f16*   qkvb    = (f16*)(ws + 2111488 + (size_t)M_ * 512 * 2); // [M][1536] f16
    f16*   aob     = xh;                                        // alias: xh dead after qkv_gemm

    cvt_x<<<2048, 256, 0, stream>>>(x, xh, M_ * 512 / 8);
    prep<<<512, 256, 0, stream>>>(Wq, Wk, Wv, Wo, bq, bk, bv, adj, Wh, Woh, biasAll, bmask);
    qkv_gemm<<<3072, 256, 0, stream>>>(xh, Wh, biasAll, qkvb);
    attn_kernel<<<128 * H_, 512, 0, stream>>>(qkvb, bmask, aob);
    o_gemm<<<1024, 256, 0, stream>>>(aob, Woh, bo, out);
}

// Round 5
// 182.304 us; speedup vs baseline: 1.3541x; 1.0466x over previous
//
#include <hip/hip_runtime.h>

#define NF 256
#define H_ 8
#define M_ 32768

typedef _Float16 f16;
typedef _Float16 f16x8 __attribute__((ext_vector_type(8)));
typedef float f32x4 __attribute__((ext_vector_type(4)));
typedef unsigned short u16x8 __attribute__((ext_vector_type(8)));

#define GLOAD16(src, dst) \
  __builtin_amdgcn_global_load_lds((const __attribute__((address_space(1))) void*)(src), \
                                   (__attribute__((address_space(3))) void*)(dst), 16, 0, 0)

// within-wave LDS fence: all outstanding ds ops complete, no compiler reordering across
#define LDS_FENCE() do { asm volatile("s_waitcnt lgkmcnt(0)" ::: "memory"); \
                         __builtin_amdgcn_sched_barrier(0); } while (0)
// raw barrier: does NOT drain vmcnt (unlike __syncthreads) — counted waits are manual
#define SBAR() asm volatile("s_barrier" ::: "memory")

// ---------------- 256^2 8-phase GEMM core (T2+T3+T4+T5) ----------------
// K=512 (8 K-tiles of 64), 8 waves (2M x 4N), per-wave out 128x64.
// LDS: 2 bufs x { A[256][64] | B[256][64] } f16 = 128 KB.
// Swizzle st_16x32-style: 16B slot s of row r holds global slot s^(r&7)
// (applied on the global source col; read with the same XOR — rule 21).

// stage one half-tile: 128 rows x 64 f16 from g[(r0+r)*512 + k0 + swz]
// into linear LDS ldst[128][64]. 2 gload_lds per thread (per wave: 2 vmcnt ops).
__device__ __forceinline__ void stageHT(const f16* __restrict__ g, int r0, int k0,
                                        f16* ldst, int wave, int lane) {
    const int key = lane >> 3;                       // == local row & 7
    const int colsw = k0 + (((lane & 7) ^ key) << 3);
#pragma unroll
    for (int i = 0; i < 2; ++i) {
        int r = i * 64 + wave * 8 + key;
        GLOAD16(g + (size_t)(r0 + r) * 512 + colsw, ldst + (i * 64 + wave * 8) * 64);
    }
}

__device__ __forceinline__ void gemm256_core(const f16* __restrict__ A, const f16* __restrict__ W,
                                             int m0, int n0, f16* lds,
                                             f32x4 (&acc)[8][4], int wave, int lane) {
    const int wr = wave & 1, wc = wave >> 1;
    const int l15 = lane & 15, l4 = lane >> 4;
    // prologue: B1(0) B2(0) A1(0) A2(0) fully landed; B1(1) B2(1) left in flight
    stageHT(W, n0,        0, lds + 16384, wave, lane);
    stageHT(W, n0 + 128,  0, lds + 24576, wave, lane);
    stageHT(A, m0,        0, lds,         wave, lane);
    stageHT(A, m0 + 128,  0, lds + 8192,  wave, lane);
    stageHT(W, n0,       64, lds + 32768 + 16384, wave, lane);
    stageHT(W, n0 + 128, 64, lds + 32768 + 24576, wave, lane);
    asm volatile("s_waitcnt vmcnt(4)" ::: "memory");
    SBAR();
#pragma unroll
    for (int t = 0; t < 8; ++t) {
        f16* bufA = lds + (t & 1) * 32768;
        f16* bufB = bufA + 16384;
        f16* nA   = lds + ((t & 1) ^ 1) * 32768;
        // P1 reads: hoist all B-frags for this K-tile (B-slot dead afterwards)
        f16x8 bfr[4][2];
#pragma unroll
        for (int j = 0; j < 4; ++j)
#pragma unroll
            for (int kk = 0; kk < 2; ++kk) {
                int rb = wc * 64 + j * 16 + l15;
                bfr[j][kk] = *reinterpret_cast<const f16x8*>(
                    bufB + rb * 64 + ((((kk << 2) + l4) ^ (rb & 7)) << 3));
            }
#pragma unroll
        for (int q = 0; q < 4; ++q) {
            // A-frags for quadrant q (rows wr*128 + q*32 .. +31)
            f16x8 afr[2][2];
#pragma unroll
            for (int rf = 0; rf < 2; ++rf)
#pragma unroll
                for (int kk = 0; kk < 2; ++kk) {
                    int ra = wr * 128 + q * 32 + rf * 16 + l15;
                    afr[rf][kk] = *reinterpret_cast<const f16x8*>(
                        bufA + ra * 64 + ((((kk << 2) + l4) ^ (ra & 7)) << 3));
                }
            // one half-tile prefetch per phase:
            //  P1/P2: A(t+1) -> other buffer (A(t-1) dead since t-1's last phase)
            //  P3/P4: B(t+2) -> CURRENT buffer's B slot (B(t) hoisted to regs at P1,
            //         all waves past their P1 lgkmcnt(0) before any wave reaches P3)
            if (q == 0 && t < 7) stageHT(A, m0,       (t + 1) * 64, nA,          wave, lane);
            if (q == 1 && t < 7) stageHT(A, m0 + 128, (t + 1) * 64, nA + 8192,   wave, lane);
            if (q == 2 && t < 6) stageHT(W, n0,       (t + 2) * 64, bufB,        wave, lane);
            if (q == 3 && t < 6) stageHT(W, n0 + 128, (t + 2) * 64, bufB + 8192, wave, lane);
            SBAR();
            LDS_FENCE();
            __builtin_amdgcn_s_setprio(1);
#pragma unroll
            for (int rf = 0; rf < 2; ++rf)
#pragma unroll
                for (int j = 0; j < 4; ++j)
#pragma unroll
                    for (int kk = 0; kk < 2; ++kk)
                        acc[q * 2 + rf][j] = __builtin_amdgcn_mfma_f32_16x16x32_f16(
                            afr[rf][kk], bfr[j][kk], acc[q * 2 + rf][j], 0, 0, 0);
            __builtin_amdgcn_s_setprio(0);
            if (q < 3) SBAR();
        }
        // K-tile boundary: require A(t+1)+B(t+1) landed (8 oldest loads);
        // allow B(t+2)'s 4 loads to stay in flight. Tail (t=6): nothing staged
        // beyond t+1 -> full drain so A(7),B(7) are guaranteed.
        if (t < 6) { asm volatile("s_waitcnt vmcnt(4)" ::: "memory"); }
        else       { asm volatile("s_waitcnt vmcnt(0)" ::: "memory"); }
        SBAR();
    }
}

// ---------------- conversion / prep (merged) ----------------

#define QSCALE 0.1803368801111204f   // (1/8) * log2(e): exp2-domain scores

__global__ void prep_all(const float* __restrict__ x, f16* __restrict__ xh,
                         const float* __restrict__ Wq, const float* __restrict__ Wk,
                         const float* __restrict__ Wv, const float* __restrict__ Wo,
                         const float* __restrict__ bq, const float* __restrict__ bk,
                         const float* __restrict__ bv, const int* __restrict__ adj,
                         f16* __restrict__ Wh, f16* __restrict__ Woh,
                         float* __restrict__ biasAll, unsigned long long* __restrict__ bmask) {
    if (blockIdx.x < 2048) {            // x -> f16
        int idx = blockIdx.x * 256 + threadIdx.x;
        for (; idx < M_ * 512 / 8; idx += 2048 * 256) {
            const float4* s = reinterpret_cast<const float4*>(x + (size_t)idx * 8);
            float4 v0 = s[0], v1 = s[1];
            f16x8 o;
            o[0] = (f16)v0.x; o[1] = (f16)v0.y; o[2] = (f16)v0.z; o[3] = (f16)v0.w;
            o[4] = (f16)v1.x; o[5] = (f16)v1.y; o[6] = (f16)v1.z; o[7] = (f16)v1.w;
            *reinterpret_cast<f16x8*>(xh + (size_t)idx * 8) = o;
        }
        return;
    }
    const int tid = (blockIdx.x - 2048) * 256 + threadIdx.x;   // 512 blocks -> 131072 threads
    {
        const float* s; f16* d; float sc = 1.0f;
        int pp = tid >> 15, off = tid & 32767;
        if (pp == 0)      { s = Wq; d = Wh;              sc = QSCALE; }
        else if (pp == 1) { s = Wk; d = Wh + 512 * 512; }
        else if (pp == 2) { s = Wv; d = Wh + 2 * 512 * 512; }
        else              { s = Wo; d = Woh; }
        const float4* sv4 = reinterpret_cast<const float4*>(s + (size_t)off * 8);
        float4 v0 = sv4[0], v1 = sv4[1];
        f16x8 o;
        o[0] = (f16)(v0.x * sc); o[1] = (f16)(v0.y * sc);
        o[2] = (f16)(v0.z * sc); o[3] = (f16)(v0.w * sc);
        o[4] = (f16)(v1.x * sc); o[5] = (f16)(v1.y * sc);
        o[6] = (f16)(v1.z * sc); o[7] = (f16)(v1.w * sc);
        *reinterpret_cast<f16x8*>(d + (size_t)off * 8) = o;
    }
    if (tid < 1536) {
        float v = (tid < 512) ? QSCALE * bq[tid] : (tid < 1024) ? bk[tid - 512] : bv[tid - 1024];
        biasAll[tid] = v;
    }
    if (tid < 65536) {   // whole waves in-branch, full exec for ballot
        unsigned long long bal = __ballot(adj[tid] > 0);
        if ((tid & 63) == 0) bmask[tid >> 6] = bal;
    }
}

// ---------------- fused QKV GEMM (256^2 8-phase) ----------------
// out = qkv [M][1536] f16 row-major. 768 blocks XCD-chunked (16 m-tiles x 6 n-tiles per XCD).

__global__ __launch_bounds__(512) void qkv_gemm(const f16* __restrict__ A, const f16* __restrict__ W,
                                                const float* __restrict__ biasAll,
                                                f16* __restrict__ out) {
    __shared__ __align__(16) f16 lds[65536];     // 128 KB
    const int tt = threadIdx.x, wave = tt >> 6, lane = tt & 63;
    const int lb = blockIdx.x, xcd = lb & 7, idx = lb >> 3;
    const int m0 = (xcd * 16 + idx / 6) * 256;
    const int n0 = (idx % 6) * 256;
    f32x4 acc[8][4] = {};
    gemm256_core(A, W, m0, n0, lds, acc, wave, lane);

    // epilogue: bias + f16, LDS transpose in 2 half-passes of [128][264]
    const int wr = wave & 1, wc = wave >> 1;
    const int l15 = lane & 15, l4 = lane >> 4;
    f16* epi = lds;
    float bb[4];
#pragma unroll
    for (int bc = 0; bc < 4; ++bc) bb[bc] = biasAll[n0 + wc * 64 + bc * 16 + l15];
#pragma unroll
    for (int half = 0; half < 2; ++half) {
        if (wr == half) {
#pragma unroll
            for (int ar = 0; ar < 8; ++ar)
#pragma unroll
                for (int bc = 0; bc < 4; ++bc)
#pragma unroll
                    for (int r = 0; r < 4; ++r)
                        epi[(ar * 16 + l4 * 4 + r) * 264 + wc * 64 + bc * 16 + l15] =
                            (f16)(acc[ar][bc][r] + bb[bc]);
        }
        LDS_FENCE();
        SBAR();
        const int rr = tt >> 5, slot = tt & 31;
#pragma unroll
        for (int p = 0; p < 8; ++p) {
            int row = p * 16 + rr;
            *reinterpret_cast<f16x8*>(out + (size_t)(m0 + half * 128 + row) * 1536 + n0 + slot * 8) =
                *reinterpret_cast<const f16x8*>(epi + row * 264 + slot * 8);
        }
        SBAR();
    }
}

// ---------------- attention (unchanged from R4) ----------------

// ---- BK=64 staging (attn K-stage), 512 threads (8 waves)
template <int NR>
__device__ __forceinline__ void stage_rows512(const f16* __restrict__ g, int ld, int coff,
                                              f16* ldsb, int wave, int lane) {
    const int rr = wave * 8 + (lane >> 3);
    const int p  = lane & 7;
#pragma unroll
    for (int i = 0; i < NR / 64; ++i) {
        int r = i * 64 + rr;
        int col = ((p ^ (r & 7)) << 3);
        GLOAD16(g + (size_t)r * ld + coff + col, ldsb + (i * 64 + wave * 8) * 64);
    }
}

__global__ __launch_bounds__(512) void attn_kernel(const f16* __restrict__ qkv,
                                                   const unsigned long long* __restrict__ bmg,
                                                   f16* __restrict__ ao) {
    __shared__ f16 Ks[256 * 64];                 // XOR-swizzled [256][64]
    __shared__ f16 Vs[64 * 256];                 // transposed V^T [dk][nf], key-swizzled
    __shared__ f16 Ps[8][16][264];               // per-wave P strip (unnormalized)
    __shared__ unsigned long long BMs[1024];     // bitmask u64[256][4] == u16[256][16]
    const int t = threadIdx.x, wave = t >> 6, lane = t & 63;
    const int l15 = lane & 15, l4 = lane >> 4;
    const int bh = blockIdx.x, bt = bh >> 3, h = bh & 7;
    const int btq = bt * 256, hq = h * 64;
    const f16* qb = qkv + (size_t)btq * 1536 + hq;
    const f16* kb = qkv + (size_t)btq * 1536 + 512 + hq;
    const f16* vb = qkv + (size_t)btq * 1536 + 1024 + hq;

    stage_rows512<256>(kb, 1536, 0, Ks, wave, lane);
    GLOAD16((const char*)bmg + (size_t)t * 16, (char*)(BMs + wave * 128));
    {   // V transpose: coalesced f16x8 row reads -> swizzled scalar LDS writes
        const int slot = t & 7, r0 = t >> 3;     // r0 in 0..63
#pragma unroll
        for (int i = 0; i < 4; ++i) {
            int nf = r0 + i * 64;
            f16x8 v = *reinterpret_cast<const f16x8*>(vb + (size_t)nf * 1536 + slot * 8);
#pragma unroll
            for (int e = 0; e < 8; ++e) {
                int dk = slot * 8 + e;
                int key = (dk & 7) ^ (dk >> 3);
                Vs[dk * 256 + (((nf >> 3) ^ key) << 3) + (nf & 7)] = v[e];
            }
        }
    }
    __syncthreads();

    for (int s = 0; s < 2; ++s) {
        const int qrow_base = wave * 32 + s * 16;

        f16x8 aq[2];
#pragma unroll
        for (int kk = 0; kk < 2; ++kk)
            aq[kk] = *reinterpret_cast<const f16x8*>(
                qb + (size_t)(qrow_base + l15) * 1536 + kk * 32 + l4 * 8);

        f32x4 sacc[16];
#pragma unroll
        for (int ct = 0; ct < 16; ++ct) sacc[ct] = (f32x4){0.f, 0.f, 0.f, 0.f};
#pragma unroll
        for (int ct = 0; ct < 16; ++ct)
#pragma unroll
            for (int kk = 0; kk < 2; ++kk) {
                int rk = ct * 16 + l15;
                int sk = kk * 4 + l4;
                f16x8 bk_ = *reinterpret_cast<const f16x8*>(Ks + rk * 64 + ((sk ^ (rk & 7)) << 3));
                sacc[ct] = __builtin_amdgcn_mfma_f32_16x16x32_f16(aq[kk], bk_, sacc[ct], 0, 0, 0);
            }

        LDS_FENCE();   // WAR: prev strip's PV reads of Ps[wave] must complete before rewrite

        float rs[4];
#pragma unroll
        for (int r = 0; r < 4; ++r) {
            const int ig = qrow_base + l4 * 4 + r;
            const u16x8* mr = reinterpret_cast<const u16x8*>(BMs + ig * 4);
            u16x8 w0 = mr[0], w1 = mr[1];
            float mx = -1e38f;
#pragma unroll
            for (int ct = 0; ct < 16; ++ct) mx = fmaxf(mx, sacc[ct][r]);
#pragma unroll
            for (int m = 1; m < 16; m <<= 1) mx = fmaxf(mx, __shfl_xor(mx, m, 64));
            float sum = 0.f;
#pragma unroll
            for (int ct = 0; ct < 16; ++ct) {
                unsigned wbit = (ct < 8) ? (unsigned)w0[ct] : (unsigned)w1[ct & 7];
                float p = __builtin_exp2f(sacc[ct][r] - mx);
                p = ((wbit >> l15) & 1u) ? p : 0.0f;
                sacc[ct][r] = p;
                sum += p;
            }
#pragma unroll
            for (int m = 1; m < 16; m <<= 1) sum += __shfl_xor(sum, m, 64);
            rs[r] = 1.0f / sum;
#pragma unroll
            for (int ct = 0; ct < 16; ++ct)
                Ps[wave][l4 * 4 + r][ct * 16 + l15] = (f16)sacc[ct][r];
        }

        LDS_FENCE();   // RAW: Ps writes visible before PV reads

        f32x4 oacc[4] = {};
#pragma unroll
        for (int kk = 0; kk < 8; ++kk) {
            f16x8 ap = *reinterpret_cast<const f16x8*>(&Ps[wave][l15][kk * 32 + l4 * 8]);
#pragma unroll
            for (int c2 = 0; c2 < 4; ++c2) {
                int dk = c2 * 16 + l15;
                int key = (dk & 7) ^ (dk >> 3);
                int sv = kk * 4 + l4;
                f16x8 bv_ = *reinterpret_cast<const f16x8*>(Vs + dk * 256 + ((sv ^ key) << 3));
                oacc[c2] = __builtin_amdgcn_mfma_f32_16x16x32_f16(ap, bv_, oacc[c2], 0, 0, 0);
            }
        }
#pragma unroll
        for (int c2 = 0; c2 < 4; ++c2)
#pragma unroll
            for (int r = 0; r < 4; ++r) {
                int nf = qrow_base + l4 * 4 + r;
                int dcol = hq + c2 * 16 + l15;
                ao[((size_t)btq + nf) * 512 + dcol] = (f16)(oacc[c2][r] * rs[r]);
            }
    }
}

// ---------------- output projection (256^2 8-phase) ----------------
// 256 blocks XCD-chunked (16 m-tiles x 2 n-tiles per XCD). f32 out + bias.

__global__ __launch_bounds__(512) void o_gemm(const f16* __restrict__ A, const f16* __restrict__ W,
                                              const float* __restrict__ bo, float* __restrict__ out) {
    __shared__ __align__(16) f16 lds[65536];
    const int tt = threadIdx.x, wave = tt >> 6, lane = tt & 63;
    const int lb = blockIdx.x, xcd = lb & 7, idx = lb >> 3;
    const int m0 = (xcd * 16 + idx / 2) * 256;
    const int n0 = (idx % 2) * 256;
    f32x4 acc[8][4] = {};
    gemm256_core(A, W, m0, n0, lds, acc, wave, lane);

    const int wr = wave & 1, wc = wave >> 1;
    const int l15 = lane & 15, l4 = lane >> 4;
    float bb[4];
#pragma unroll
    for (int bc = 0; bc < 4; ++bc) bb[bc] = bo[n0 + wc * 64 + bc * 16 + l15];
#pragma unroll
    for (int ar = 0; ar < 8; ++ar)
#pragma unroll
        for (int bc = 0; bc < 4; ++bc) {
            int ng = n0 + wc * 64 + bc * 16 + l15;
#pragma unroll
            for (int r = 0; r < 4; ++r) {
                int mg = m0 + wr * 128 + ar * 16 + l4 * 4 + r;
                out[(size_t)mg * 512 + ng] = acc[ar][bc][r] + bb[bc];
            }
        }
}

// ---------------- launch ----------------

extern "C" void kernel_launch(void* const* d_in, const int* in_sizes, int n_in,
                              void* d_out, int out_size, void* d_ws, size_t ws_size,
                              hipStream_t stream) {
    const float* x   = (const float*)d_in[0];
    const int*   adj = (const int*)d_in[1];
    const float* Wq  = (const float*)d_in[2];
    const float* bq  = (const float*)d_in[3];
    const float* Wk  = (const float*)d_in[4];
    const float* bk  = (const float*)d_in[5];
    const float* Wv  = (const float*)d_in[6];
    const float* bv  = (const float*)d_in[7];
    const float* Wo  = (const float*)d_in[8];
    const float* bo  = (const float*)d_in[9];
    float* out = (float*)d_out;

    char* ws = (char*)d_ws;
    f16*   Wh      = (f16*)ws;                                  // [1536][512]  1572864 B
    f16*   Woh     = (f16*)(ws + 1572864);                      // [512][512]    524288 B
    float* biasAll = (float*)(ws + 2097152);                    // [1536]          6144 B
    unsigned long long* bmask = (unsigned long long*)(ws + 2103296); // [1024]     8192 B
    f16*   xh      = (f16*)(ws + 2111488);                      // [M][512] f16, reused as ao
    f16*   qkvb    = (f16*)(ws + 2111488 + (size_t)M_ * 512 * 2); // [M][1536] f16
    f16*   aob     = xh;                                        // alias: xh dead after qkv_gemm

    prep_all<<<2560, 256, 0, stream>>>(x, xh, Wq, Wk, Wv, Wo, bq, bk, bv, adj,
                                       Wh, Woh, biasAll, bmask);
    qkv_gemm<<<768, 512, 0, stream>>>(xh, Wh, biasAll, qkvb);
    attn_kernel<<<128 * H_, 512, 0, stream>>>(qkvb, bmask, aob);
    o_gemm<<<256, 512, 0, stream>>>(aob, Woh, bo, out);
}